// Round 1
// baseline (496.442 us; speedup 1.0000x reference)
//
#include <hip/hip_runtime.h>

// Per-joint 3D Euclidean distance, mean over B*21 joints.
// B = 1048576, NUM_JOINTS = 21 -> 66,060,288 floats per input (264 MB each).
// Pure HBM-streaming reduction; floor ~= 528 MB / 6.3 TB/s ~= 84 us.
//
// Layout trick: 21 joints * 3 floats = 63 floats/row; globally the joint
// stream is contiguous, so 4 joints = 12 floats = 3 float4 loads per thread,
// exactly divisible (66,060,288 / 12 = 5,505,024). No tail handling.

#define TPB 256
#define BLOCKS 2048  // 2048 blocks * 4 waves = 8192 waves = 32 waves/CU nominal

__global__ __launch_bounds__(TPB) void joint_dist_partial(
    const float* __restrict__ pred,
    const float* __restrict__ target,
    float* __restrict__ partial,
    int nelem)  // number of 12-float groups
{
    const float4* __restrict__ p4 = (const float4*)pred;
    const float4* __restrict__ t4 = (const float4*)target;

    int tid    = blockIdx.x * TPB + threadIdx.x;
    int stride = gridDim.x * TPB;

    float acc = 0.0f;
    for (int i = tid; i < nelem; i += stride) {
        int base = i * 3;
        float4 a0 = p4[base + 0];
        float4 a1 = p4[base + 1];
        float4 a2 = p4[base + 2];
        float4 b0 = t4[base + 0];
        float4 b1 = t4[base + 1];
        float4 b2 = t4[base + 2];

        float dx, dy, dz;
        // joint 0: floats 0..2
        dx = a0.x - b0.x; dy = a0.y - b0.y; dz = a0.z - b0.z;
        acc += sqrtf(dx * dx + dy * dy + dz * dz);
        // joint 1: floats 3..5
        dx = a0.w - b0.w; dy = a1.x - b1.x; dz = a1.y - b1.y;
        acc += sqrtf(dx * dx + dy * dy + dz * dz);
        // joint 2: floats 6..8
        dx = a1.z - b1.z; dy = a1.w - b1.w; dz = a2.x - b2.x;
        acc += sqrtf(dx * dx + dy * dy + dz * dz);
        // joint 3: floats 9..11
        dx = a2.y - b2.y; dy = a2.z - b2.z; dz = a2.w - b2.w;
        acc += sqrtf(dx * dx + dy * dy + dz * dz);
    }

    // 64-lane wave reduction
    #pragma unroll
    for (int off = 32; off > 0; off >>= 1)
        acc += __shfl_down(acc, off, 64);

    __shared__ float wsum[TPB / 64];
    int lane = threadIdx.x & 63;
    int wid  = threadIdx.x >> 6;
    if (lane == 0) wsum[wid] = acc;
    __syncthreads();

    if (threadIdx.x == 0) {
        // every block writes its slot unconditionally -> safe vs 0xAA poison
        partial[blockIdx.x] = wsum[0] + wsum[1] + wsum[2] + wsum[3];
    }
}

__global__ __launch_bounds__(TPB) void joint_dist_final(
    const float* __restrict__ partial,
    float* __restrict__ out,
    int nblocks,
    float inv_count)
{
    float acc = 0.0f;
    for (int i = threadIdx.x; i < nblocks; i += TPB)
        acc += partial[i];

    #pragma unroll
    for (int off = 32; off > 0; off >>= 1)
        acc += __shfl_down(acc, off, 64);

    __shared__ float wsum[TPB / 64];
    int lane = threadIdx.x & 63;
    int wid  = threadIdx.x >> 6;
    if (lane == 0) wsum[wid] = acc;
    __syncthreads();

    if (threadIdx.x == 0)
        out[0] = (wsum[0] + wsum[1] + wsum[2] + wsum[3]) * inv_count;
}

extern "C" void kernel_launch(void* const* d_in, const int* in_sizes, int n_in,
                              void* d_out, int out_size, void* d_ws, size_t ws_size,
                              hipStream_t stream) {
    const float* pred   = (const float*)d_in[0];
    const float* target = (const float*)d_in[1];
    float* out     = (float*)d_out;
    float* partial = (float*)d_ws;  // BLOCKS floats = 8 KB scratch

    int total_floats = in_sizes[0];        // 66,060,288
    int nelem        = total_floats / 12;  // 5,505,024 four-joint groups
    int njoints      = total_floats / 3;   // 22,020,096

    joint_dist_partial<<<BLOCKS, TPB, 0, stream>>>(pred, target, partial, nelem);
    joint_dist_final<<<1, TPB, 0, stream>>>(partial, out, BLOCKS,
                                            1.0f / (float)njoints);
}